// Round 1
// baseline (651.529 us; speedup 1.0000x reference)
//
#include <hip/hip_runtime.h>
#include <hip/hip_bf16.h>
#include <math.h>

// Problem constants
#define N_PRED 1200      // bs*Q
#define N_TGT  200
#define T_PAD  208       // 13 tiles of 16
#define NCLS   80
#define W_OUT  160
#define W_IN   320
#define HW     25600     // 160*160 == K of the GEMMs
#define K_TOT  25600
#define KS     25        // K-split factor
#define K_CHUNK 1024     // K_TOT / KS
#define BK     64        // K per LDS stage
#define MT     19        // ceil(1200/64) M-tiles of 64
#define LDA    80        // LDS row stride in ushorts (64 + 16 pad: keeps 16B align, breaks worst conflicts)
#define LDB    80

typedef __bf16 bf16x8 __attribute__((ext_vector_type(8)));
typedef float  f32x4  __attribute__((ext_vector_type(4)));

__device__ __forceinline__ unsigned short f2bf(float f) {
    unsigned int u = __float_as_uint(f);
    u = u + 0x7FFFu + ((u >> 16) & 1u);   // round-to-nearest-even
    return (unsigned short)(u >> 16);
}

// jax.image.resize(antialias=True, bilinear, 320->160): 4 taps, weights
// {1,3,3,1}/8 interior; boundary renormalized ({3,3,1}/7).
__device__ __forceinline__ void taps(int i, int& i0, float w[4]) {
    if (i == 0)            { i0 = 0;       w[0]=3.f/7.f; w[1]=3.f/7.f; w[2]=1.f/7.f; w[3]=0.f; }
    else if (i == W_OUT-1) { i0 = 2*i - 2; w[0]=0.f;     w[1]=1.f/7.f; w[2]=3.f/7.f; w[3]=3.f/7.f; }
    else                   { i0 = 2*i - 1; w[0]=0.125f;  w[1]=0.375f;  w[2]=0.375f;  w[3]=0.125f; }
}

// K1: resize tgt masks 320x320 -> 160x160, store bf16 [T_PAD][25600], colsum per t.
// grid (4, T_PAD) x 256. tgt_sum must be pre-zeroed (atomicAdd).
__global__ void resize_kernel(const float* __restrict__ tm,
                              unsigned short* __restrict__ tgt_bf,
                              float* __restrict__ tgt_sum) {
    const int t = blockIdx.y, q = blockIdx.x, tid = threadIdx.x;
    if (t >= N_TGT) {   // zero the pad rows (ws is poisoned 0xAA)
        uint4 z = make_uint4(0,0,0,0);
        uint4* dst = (uint4*)(tgt_bf + (size_t)t * HW) + q * (HW/8/4);
        for (int u = tid; u < HW/8/4; u += 256) dst[u] = z;
        return;
    }
    const float* src = tm + (size_t)t * (W_IN * W_IN);
    float part = 0.f;
    const int p0 = q * (HW/4);
    for (int pp = tid; pp < HW/4; pp += 256) {
        const int p = p0 + pp;
        const int i = p / W_OUT, j = p % W_OUT;
        int r0, c0; float wr[4], wc[4];
        taps(i, r0, wr); taps(j, c0, wc);
        float v = 0.f;
        #pragma unroll
        for (int a = 0; a < 4; a++) {
            const float* row = src + (size_t)(r0 + a) * W_IN + c0;
            float h = wc[0]*row[0] + wc[1]*row[1] + wc[2]*row[2] + wc[3]*row[3];
            v += wr[a] * h;
        }
        tgt_bf[(size_t)t * HW + p] = f2bf(v);
        part += v;
    }
    __shared__ float red[256];
    red[tid] = part; __syncthreads();
    for (int s = 128; s > 0; s >>= 1) { if (tid < s) red[tid] += red[tid + s]; __syncthreads(); }
    if (tid == 0) atomicAdd(&tgt_sum[t], red[0]);
}

// K2: fused dual GEMM.  S1 = sigma(X) @ tgt^T, S2 = X @ tgt^T, K-split into
// partials; also rowsum(sigma) and rowsum(-softplus) via atomics.
// grid (KS, MT) x 256 threads (4 waves; wave w owns m-rows [w*16, w*16+16)).
__global__ __launch_bounds__(256, 2)
void gemm_kernel(const float* __restrict__ pm,
                 const unsigned short* __restrict__ tgt_bf,
                 float* __restrict__ P1, float* __restrict__ P2,
                 float* __restrict__ sig_rs, float* __restrict__ l1p_rs) {
    const int ks = blockIdx.x, mtile = blockIdx.y;
    const int tid = threadIdx.x;
    const int wave = tid >> 6, lane = tid & 63;
    const int quad = lane >> 4, l16 = lane & 15;

    __shared__ unsigned short ldsAX[64 * LDA];
    __shared__ unsigned short ldsAS[64 * LDA];
    __shared__ unsigned short ldsB[T_PAD * LDB];

    f32x4 accS[13], accX[13];
    #pragma unroll
    for (int i = 0; i < 13; i++) { accS[i] = (f32x4)(0.f); accX[i] = (f32x4)(0.f); }
    float sig_part[4] = {0.f,0.f,0.f,0.f};
    float l1p_part[4] = {0.f,0.f,0.f,0.f};

    const int m0 = mtile * 64;
    const int arow = tid >> 4;   // 0..15 : row within 16-row group
    const int ac   = tid & 15;   // float4 column index
    const int k0   = ks * K_CHUNK;

    for (int ki = 0; ki < K_CHUNK / BK; ki++) {
        const int k = k0 + ki * BK;
        // stage B tile: 208 rows x 64 k (bf16)
        for (int u = tid; u < T_PAD * 8; u += 256) {
            const int br = u >> 3, bc = u & 7;
            uint4 d = *(const uint4*)(tgt_bf + (size_t)br * K_TOT + k + bc * 8);
            *(uint4*)&ldsB[br * LDB + bc * 8] = d;
        }
        // stage A tile: 64 rows x 64 k, fp32 -> bf16 X and bf16 sigma(X)
        #pragma unroll
        for (int j = 0; j < 4; j++) {
            const int rl = j * 16 + arow;
            const int rg = m0 + rl;
            float4 x = make_float4(0.f, 0.f, 0.f, 0.f);
            if (rg < N_PRED) x = *(const float4*)(pm + (size_t)rg * K_TOT + k + ac * 4);
            float xs[4] = {x.x, x.y, x.z, x.w};
            unsigned short bx[4], bs[4];
            float ssum = 0.f, lsum = 0.f;
            #pragma unroll
            for (int e = 0; e < 4; e++) {
                const float xv = xs[e];
                const float tt = __expf(-fabsf(xv));
                const float inv = 1.f / (1.f + tt);
                const float sg = (xv >= 0.f) ? inv : tt * inv;
                const float sp = log1pf(tt) + fmaxf(xv, 0.f);  // softplus(x); clamp -100 never fires (|x|<~7)
                ssum += sg; lsum -= sp;
                bx[e] = f2bf(xv); bs[e] = f2bf(sg);
            }
            if (rg < N_PRED) { sig_part[j] += ssum; l1p_part[j] += lsum; }
            uint2 px = make_uint2((unsigned)bx[0] | ((unsigned)bx[1] << 16),
                                  (unsigned)bx[2] | ((unsigned)bx[3] << 16));
            uint2 ps = make_uint2((unsigned)bs[0] | ((unsigned)bs[1] << 16),
                                  (unsigned)bs[2] | ((unsigned)bs[3] << 16));
            *(uint2*)&ldsAX[rl * LDA + ac * 4] = px;
            *(uint2*)&ldsAS[rl * LDA + ac * 4] = ps;
        }
        __syncthreads();
        // MFMA: A frag = A[m=lane&15][k=quad*8+j]; B frag = tgt[t=lane&15][k=quad*8+j]
        #pragma unroll
        for (int kk = 0; kk < 2; kk++) {
            const int koff = kk * 32 + quad * 8;
            bf16x8 aX = *(const bf16x8*)&ldsAX[(wave * 16 + l16) * LDA + koff];
            bf16x8 aS = *(const bf16x8*)&ldsAS[(wave * 16 + l16) * LDA + koff];
            #pragma unroll
            for (int tt = 0; tt < 13; tt++) {
                bf16x8 b = *(const bf16x8*)&ldsB[(tt * 16 + l16) * LDB + koff];
                accS[tt] = __builtin_amdgcn_mfma_f32_16x16x32_bf16(aS, b, accS[tt], 0, 0, 0);
                accX[tt] = __builtin_amdgcn_mfma_f32_16x16x32_bf16(aX, b, accX[tt], 0, 0, 0);
            }
        }
        __syncthreads();
    }
    // epilogue: C/D layout col=lane&15, row=quad*4+reg  (verified layout)
    const size_t base = ((size_t)(mtile * KS + ks)) * 64 * T_PAD;
    #pragma unroll
    for (int tt = 0; tt < 13; tt++) {
        #pragma unroll
        for (int r = 0; r < 4; r++) {
            const int rl = wave * 16 + quad * 4 + r;
            const int col = tt * 16 + l16;
            P1[base + (size_t)rl * T_PAD + col] = accS[tt][r];
            P2[base + (size_t)rl * T_PAD + col] = accX[tt][r];
        }
    }
    #pragma unroll
    for (int j = 0; j < 4; j++) {
        const int rg = m0 + j * 16 + arow;
        if (rg < N_PRED) {
            atomicAdd(sig_rs + rg, sig_part[j]);
            atomicAdd(l1p_rs + rg, l1p_part[j]);
        }
    }
}

// K3: reduce K-split partials + class/bbox/giou + assemble final cost.
__global__ void combine_kernel(const float* __restrict__ pred_logits,
                               const float* __restrict__ pred_boxes,
                               const int*   __restrict__ tgt_ids,
                               const float* __restrict__ tgt_bbox,
                               const float* __restrict__ P1, const float* __restrict__ P2,
                               const float* __restrict__ sig_rs, const float* __restrict__ l1p_rs,
                               const float* __restrict__ tgt_sum,
                               float* __restrict__ out) {
    const int e = blockIdx.x * 256 + threadIdx.x;
    if (e >= N_PRED * N_TGT) return;
    const int n = e / N_TGT, t = e - n * N_TGT;
    const int mtile = n >> 6, mrow = n & 63;

    const size_t pb = ((size_t)mtile * KS * 64 + mrow) * T_PAD + t;
    float s1 = 0.f, s2 = 0.f;
    for (int ks = 0; ks < KS; ks++) {
        s1 += P1[pb + (size_t)ks * 64 * T_PAD];
        s2 += P2[pb + (size_t)ks * 64 * T_PAD];
    }
    // dice
    const float denom = sig_rs[n] + tgt_sum[t];
    const float cost_dice = -(2.f * s1 + 1.f) / (fmaxf(denom, 1e-6f) + 1.f);
    // mask BCE: -(S2 + rowsum(log_1mp))/HW
    const float cost_mask = -(s2 + l1p_rs[n]) / (float)HW;
    // class
    const int id = tgt_ids[t];
    const float lg = pred_logits[(size_t)n * NCLS + id];
    const float p = 1.f / (1.f + __expf(-lg));
    // bbox L1
    const float4 ob = *(const float4*)(pred_boxes + (size_t)n * 4);
    const float4 tb = *(const float4*)(tgt_bbox + (size_t)t * 4);
    const float l1 = fabsf(ob.x - tb.x) + fabsf(ob.y - tb.y) + fabsf(ob.z - tb.z) + fabsf(ob.w - tb.w);
    // giou
    const float ax0 = ob.x - 0.5f*ob.z, ay0 = ob.y - 0.5f*ob.w;
    const float ax1 = ob.x + 0.5f*ob.z, ay1 = ob.y + 0.5f*ob.w;
    const float bx0 = tb.x - 0.5f*tb.z, by0 = tb.y - 0.5f*tb.w;
    const float bx1 = tb.x + 0.5f*tb.z, by1 = tb.y + 0.5f*tb.w;
    const float areaA = (ax1 - ax0) * (ay1 - ay0);
    const float areaB = (bx1 - bx0) * (by1 - by0);
    const float iw = fmaxf(fminf(ax1, bx1) - fmaxf(ax0, bx0), 0.f);
    const float ih = fmaxf(fminf(ay1, by1) - fmaxf(ay0, by0), 0.f);
    const float inter = iw * ih;
    const float uni = areaA + areaB - inter;
    const float iou = inter / uni;
    const float cw = fmaxf(fmaxf(ax1, bx1) - fminf(ax0, bx0), 0.f);
    const float ch = fmaxf(fmaxf(ay1, by1) - fminf(ay0, by0), 0.f);
    const float areaC = cw * ch;
    const float giou = iou - (areaC - uni) / areaC;

    out[e] = 5.f * l1 + 2.f * (-giou) + 2.f * (-p) + 2.f * cost_mask + 2.f * cost_dice;
}

extern "C" void kernel_launch(void* const* d_in, const int* in_sizes, int n_in,
                              void* d_out, int out_size, void* d_ws, size_t ws_size,
                              hipStream_t stream) {
    const float* pred_logits = (const float*)d_in[0];
    const float* pred_boxes  = (const float*)d_in[1];
    const float* pred_masks  = (const float*)d_in[2];
    const int*   tgt_ids     = (const int*)d_in[3];
    const float* tgt_bbox    = (const float*)d_in[4];
    const float* tgt_masks   = (const float*)d_in[5];
    float* out = (float*)d_out;

    // workspace carving (ws poisoned 0xAA each call — everything re-written/zeroed)
    char* ws = (char*)d_ws;
    size_t off = 0;
    unsigned short* tgt_bf = (unsigned short*)(ws + off);
    off += (size_t)T_PAD * K_TOT * sizeof(unsigned short);       // 10,649,600
    off = (off + 255) & ~(size_t)255;
    float* sig_rs = (float*)(ws + off);                           // [1216]
    float* l1p_rs = sig_rs + 1216;                                // [1216]
    float* tgt_sum = l1p_rs + 1216;                               // [208]
    size_t zero_bytes = (size_t)(1216 + 1216 + 208) * sizeof(float);
    off += zero_bytes;
    off = (off + 255) & ~(size_t)255;
    float* P1 = (float*)(ws + off);
    off += (size_t)MT * KS * 64 * T_PAD * sizeof(float);          // 25,292,800
    float* P2 = (float*)(ws + off);
    off += (size_t)MT * KS * 64 * T_PAD * sizeof(float);

    hipMemsetAsync(sig_rs, 0, zero_bytes, stream);
    hipLaunchKernelGGL(resize_kernel, dim3(4, T_PAD), dim3(256), 0, stream,
                       tgt_masks, tgt_bf, tgt_sum);
    hipLaunchKernelGGL(gemm_kernel, dim3(KS, MT), dim3(256), 0, stream,
                       pred_masks, tgt_bf, P1, P2, sig_rs, l1p_rs);
    hipLaunchKernelGGL(combine_kernel, dim3((N_PRED * N_TGT + 255) / 256), dim3(256), 0, stream,
                       pred_logits, pred_boxes, tgt_ids, tgt_bbox,
                       P1, P2, sig_rs, l1p_rs, tgt_sum, out);
}

// Round 2
// 311.243 us; speedup vs baseline: 2.0933x; 2.0933x over previous
//
#include <hip/hip_runtime.h>
#include <math.h>

// Problem constants
#define N_PRED 1200      // bs*Q
#define N_TGT  200
#define T_PAD  208       // 13 tiles of 16
#define NCLS   80
#define W_OUT  160
#define W_IN   320
#define HW     25600     // 160*160 == K of the GEMMs
#define K_TOT  25600
#define KS     25        // K-split factor
#define K_CHUNK 1024     // K_TOT / KS
#define BK     64        // K per LDS stage
#define MT     19        // ceil(1200/64) M-tiles of 64
#define LDA    72        // LDS row stride in ushorts: 144 B/row -> 16B-aligned, bank stride 36 (conflict-free-ish)
#define LDB    72

typedef __bf16 bf16x8 __attribute__((ext_vector_type(8)));
typedef float  f32x4  __attribute__((ext_vector_type(4)));

__device__ __forceinline__ unsigned short f2bf(float f) {
    unsigned int u = __float_as_uint(f);
    u = u + 0x7FFFu + ((u >> 16) & 1u);   // round-to-nearest-even
    return (unsigned short)(u >> 16);
}

// jax.image.resize(antialias=True, bilinear, 320->160): 4 taps, weights
// {1,3,3,1}/8 interior; boundary renormalized ({3,3,1}/7).
__device__ __forceinline__ void taps(int i, int& i0, float w[4]) {
    if (i == 0)            { i0 = 0;       w[0]=3.f/7.f; w[1]=3.f/7.f; w[2]=1.f/7.f; w[3]=0.f; }
    else if (i == W_OUT-1) { i0 = 2*i - 2; w[0]=0.f;     w[1]=1.f/7.f; w[2]=3.f/7.f; w[3]=3.f/7.f; }
    else                   { i0 = 2*i - 1; w[0]=0.125f;  w[1]=0.375f;  w[2]=0.375f;  w[3]=0.125f; }
}

// K1: resize tgt masks 320x320 -> 160x160, store bf16 [T_PAD][25600], colsum per t.
// grid (4, T_PAD) x 256. tgt_sum must be pre-zeroed (atomicAdd).
__global__ void resize_kernel(const float* __restrict__ tm,
                              unsigned short* __restrict__ tgt_bf,
                              float* __restrict__ tgt_sum) {
    const int t = blockIdx.y, q = blockIdx.x, tid = threadIdx.x;
    if (t >= N_TGT) {   // zero the pad rows (ws is poisoned 0xAA)
        uint4 z = make_uint4(0,0,0,0);
        uint4* dst = (uint4*)(tgt_bf + (size_t)t * HW) + q * (HW/8/4);
        for (int u = tid; u < HW/8/4; u += 256) dst[u] = z;
        return;
    }
    const float* src = tm + (size_t)t * (W_IN * W_IN);
    float part = 0.f;
    const int p0 = q * (HW/4);
    for (int pp = tid; pp < HW/4; pp += 256) {
        const int p = p0 + pp;
        const int i = p / W_OUT, j = p % W_OUT;
        int r0, c0; float wr[4], wc[4];
        taps(i, r0, wr); taps(j, c0, wc);
        float v = 0.f;
        #pragma unroll
        for (int a = 0; a < 4; a++) {
            const float* row = src + (size_t)(r0 + a) * W_IN + c0;
            float h = wc[0]*row[0] + wc[1]*row[1] + wc[2]*row[2] + wc[3]*row[3];
            v += wr[a] * h;
        }
        tgt_bf[(size_t)t * HW + p] = f2bf(v);
        part += v;
    }
    __shared__ float red[256];
    red[tid] = part; __syncthreads();
    for (int s = 128; s > 0; s >>= 1) { if (tid < s) red[tid] += red[tid + s]; __syncthreads(); }
    if (tid == 0) atomicAdd(&tgt_sum[t], red[0]);
}

// K2: per-row sums of sigma(x) and -softplus(x) over pred_masks.
// One block per row (1200 blocks): no atomics, no pre-zero needed.
__global__ void rowsum_kernel(const float* __restrict__ pm,
                              float* __restrict__ sig_rs,
                              float* __restrict__ l1p_rs) {
    const int n = blockIdx.x, tid = threadIdx.x;
    const float* row = pm + (size_t)n * HW;
    float s = 0.f, l = 0.f;
    #pragma unroll
    for (int i = 0; i < 25; i++) {
        float4 x4 = *(const float4*)(row + tid * 4 + i * 1024);
        float xs[4] = {x4.x, x4.y, x4.z, x4.w};
        #pragma unroll
        for (int e = 0; e < 4; e++) {
            const float xv = xs[e];
            const float t  = __expf(-fabsf(xv));
            const float inv = __builtin_amdgcn_rcpf(1.f + t);
            s += (xv >= 0.f) ? inv : (1.f - inv);
            l -= __logf(1.f + t) + fmaxf(xv, 0.f);   // -softplus; -100 clamp never fires (|x|<~6)
        }
    }
    __shared__ float redS[256], redL[256];
    redS[tid] = s; redL[tid] = l; __syncthreads();
    for (int st = 128; st > 0; st >>= 1) {
        if (tid < st) { redS[tid] += redS[tid + st]; redL[tid] += redL[tid + st]; }
        __syncthreads();
    }
    if (tid == 0) { sig_rs[n] = redS[0]; l1p_rs[n] = redL[0]; }
}

// ---- K3: fused dual GEMM, spill-proof accumulators, reg-prefetch pipeline ----
#define DECL13(p) f32x4 p##0={0,0,0,0}, p##1={0,0,0,0}, p##2={0,0,0,0}, p##3={0,0,0,0}, \
    p##4={0,0,0,0}, p##5={0,0,0,0}, p##6={0,0,0,0}, p##7={0,0,0,0}, p##8={0,0,0,0}, \
    p##9={0,0,0,0}, p##10={0,0,0,0}, p##11={0,0,0,0}, p##12={0,0,0,0}

#define STEP(tt) { bf16x8 b = *(const bf16x8*)&ldsB[((tt)*16 + l16) * LDB + koff]; \
    accS##tt = __builtin_amdgcn_mfma_f32_16x16x32_bf16(aS, b, accS##tt, 0, 0, 0); \
    accX##tt = __builtin_amdgcn_mfma_f32_16x16x32_bf16(aX, b, accX##tt, 0, 0, 0); }

#define CONVW(J, RA) { \
    const float x0 = RA.x, x1 = RA.y, x2 = RA.z, x3 = RA.w; \
    const float s0 = __builtin_amdgcn_rcpf(1.f + __expf(-x0)); \
    const float s1 = __builtin_amdgcn_rcpf(1.f + __expf(-x1)); \
    const float s2 = __builtin_amdgcn_rcpf(1.f + __expf(-x2)); \
    const float s3 = __builtin_amdgcn_rcpf(1.f + __expf(-x3)); \
    const unsigned px0 = (unsigned)f2bf(x0) | ((unsigned)f2bf(x1) << 16); \
    const unsigned px1 = (unsigned)f2bf(x2) | ((unsigned)f2bf(x3) << 16); \
    const unsigned ps0 = (unsigned)f2bf(s0) | ((unsigned)f2bf(s1) << 16); \
    const unsigned ps1 = (unsigned)f2bf(s2) | ((unsigned)f2bf(s3) << 16); \
    *(uint2*)&ldsAX[((J)*16 + arow) * LDA + ac * 4] = make_uint2(px0, px1); \
    *(uint2*)&ldsAS[((J)*16 + arow) * LDA + ac * 4] = make_uint2(ps0, ps1); }

#define EPI(tt) { const size_t b0 = base + (size_t)(wave * 16 + quad * 4) * T_PAD + (tt) * 16 + l16; \
    P1[b0] = accS##tt[0]; P1[b0 + T_PAD] = accS##tt[1]; \
    P1[b0 + 2*T_PAD] = accS##tt[2]; P1[b0 + 3*T_PAD] = accS##tt[3]; \
    P2[b0] = accX##tt[0]; P2[b0 + T_PAD] = accX##tt[1]; \
    P2[b0 + 2*T_PAD] = accX##tt[2]; P2[b0 + 3*T_PAD] = accX##tt[3]; }

__global__ __launch_bounds__(256, 2)
void gemm_kernel(const float* __restrict__ pm,
                 const unsigned short* __restrict__ tgt_bf,
                 float* __restrict__ P1, float* __restrict__ P2) {
    const int ks = blockIdx.x, mtile = blockIdx.y;
    const int tid = threadIdx.x;
    const int wave = tid >> 6, lane = tid & 63;
    const int quad = lane >> 4, l16 = lane & 15;

    __shared__ unsigned short ldsAX[64 * LDA];
    __shared__ unsigned short ldsAS[64 * LDA];
    __shared__ unsigned short ldsB[T_PAD * LDB];

    DECL13(accS);
    DECL13(accX);

    const int m0 = mtile * 64;
    const int arow = tid >> 4;   // 0..15: row within 16-row group
    const int ac   = tid & 15;   // float4 column index
    const int k0   = ks * K_CHUNK;

    // Clamped A row pointers (rows >= N_PRED read row 1199; their outputs are never consumed)
    int r0i = m0 + 0*16 + arow; if (r0i > N_PRED-1) r0i = N_PRED-1;
    int r1i = m0 + 1*16 + arow; if (r1i > N_PRED-1) r1i = N_PRED-1;
    int r2i = m0 + 2*16 + arow; if (r2i > N_PRED-1) r2i = N_PRED-1;
    int r3i = m0 + 3*16 + arow; if (r3i > N_PRED-1) r3i = N_PRED-1;
    const float* ap0 = pm + (size_t)r0i * K_TOT + ac * 4;
    const float* ap1 = pm + (size_t)r1i * K_TOT + ac * 4;
    const float* ap2 = pm + (size_t)r2i * K_TOT + ac * 4;
    const float* ap3 = pm + (size_t)r3i * K_TOT + ac * 4;

    // B staging addresses: 1664 uint4 per 64-K tile; thread does 6 + 1 conditional
    const int bu  = tid;                 // u = tid + i*256; row u>>3, col-ush (u&7)*8

    // ---- prefetch tile 0 ----
    float4 rA0 = *(const float4*)(ap0 + k0);
    float4 rA1 = *(const float4*)(ap1 + k0);
    float4 rA2 = *(const float4*)(ap2 + k0);
    float4 rA3 = *(const float4*)(ap3 + k0);
    uint4 rB0, rB1, rB2, rB3, rB4, rB5, rB6;
    {
        const unsigned short* bp = tgt_bf + k0;
        rB0 = *(const uint4*)(bp + (size_t)((bu       ) >> 3) * K_TOT + ((bu       ) & 7) * 8);
        rB1 = *(const uint4*)(bp + (size_t)((bu +  256) >> 3) * K_TOT + ((bu +  256) & 7) * 8);
        rB2 = *(const uint4*)(bp + (size_t)((bu +  512) >> 3) * K_TOT + ((bu +  512) & 7) * 8);
        rB3 = *(const uint4*)(bp + (size_t)((bu +  768) >> 3) * K_TOT + ((bu +  768) & 7) * 8);
        rB4 = *(const uint4*)(bp + (size_t)((bu + 1024) >> 3) * K_TOT + ((bu + 1024) & 7) * 8);
        rB5 = *(const uint4*)(bp + (size_t)((bu + 1280) >> 3) * K_TOT + ((bu + 1280) & 7) * 8);
        if (tid < 128)
            rB6 = *(const uint4*)(bp + (size_t)((bu + 1536) >> 3) * K_TOT + ((bu + 1536) & 7) * 8);
    }

    for (int ki = 0; ki < K_CHUNK / BK; ki++) {
        __syncthreads();                       // previous MFMA phase done -> LDS reusable
        // stage A (convert fp32 -> bf16 X and bf16 sigma) + B from prefetched regs
        CONVW(0, rA0); CONVW(1, rA1); CONVW(2, rA2); CONVW(3, rA3);
        *(uint4*)&ldsB[((bu       ) >> 3) * LDB + ((bu       ) & 7) * 8] = rB0;
        *(uint4*)&ldsB[((bu +  256) >> 3) * LDB + ((bu +  256) & 7) * 8] = rB1;
        *(uint4*)&ldsB[((bu +  512) >> 3) * LDB + ((bu +  512) & 7) * 8] = rB2;
        *(uint4*)&ldsB[((bu +  768) >> 3) * LDB + ((bu +  768) & 7) * 8] = rB3;
        *(uint4*)&ldsB[((bu + 1024) >> 3) * LDB + ((bu + 1024) & 7) * 8] = rB4;
        *(uint4*)&ldsB[((bu + 1280) >> 3) * LDB + ((bu + 1280) & 7) * 8] = rB5;
        if (tid < 128)
            *(uint4*)&ldsB[((bu + 1536) >> 3) * LDB + ((bu + 1536) & 7) * 8] = rB6;
        __syncthreads();
        // issue next tile's global loads; they overlap the MFMA phase below
        if (ki != K_CHUNK / BK - 1) {
            const int kn = k0 + (ki + 1) * BK;
            rA0 = *(const float4*)(ap0 + kn);
            rA1 = *(const float4*)(ap1 + kn);
            rA2 = *(const float4*)(ap2 + kn);
            rA3 = *(const float4*)(ap3 + kn);
            const unsigned short* bp = tgt_bf + kn;
            rB0 = *(const uint4*)(bp + (size_t)((bu       ) >> 3) * K_TOT + ((bu       ) & 7) * 8);
            rB1 = *(const uint4*)(bp + (size_t)((bu +  256) >> 3) * K_TOT + ((bu +  256) & 7) * 8);
            rB2 = *(const uint4*)(bp + (size_t)((bu +  512) >> 3) * K_TOT + ((bu +  512) & 7) * 8);
            rB3 = *(const uint4*)(bp + (size_t)((bu +  768) >> 3) * K_TOT + ((bu +  768) & 7) * 8);
            rB4 = *(const uint4*)(bp + (size_t)((bu + 1024) >> 3) * K_TOT + ((bu + 1024) & 7) * 8);
            rB5 = *(const uint4*)(bp + (size_t)((bu + 1280) >> 3) * K_TOT + ((bu + 1280) & 7) * 8);
            if (tid < 128)
                rB6 = *(const uint4*)(bp + (size_t)((bu + 1536) >> 3) * K_TOT + ((bu + 1536) & 7) * 8);
        }
        // MFMA phase: A frag = A[m=lane&15][k=quad*8+j]; B frag = tgt[t=lane&15][k=quad*8+j]
        #pragma unroll
        for (int kk = 0; kk < 2; kk++) {
            const int koff = kk * 32 + quad * 8;
            bf16x8 aX = *(const bf16x8*)&ldsAX[(wave * 16 + l16) * LDA + koff];
            bf16x8 aS = *(const bf16x8*)&ldsAS[(wave * 16 + l16) * LDA + koff];
            STEP(0); STEP(1); STEP(2); STEP(3); STEP(4); STEP(5); STEP(6);
            STEP(7); STEP(8); STEP(9); STEP(10); STEP(11); STEP(12);
        }
    }
    // epilogue: C/D layout col=lane&15, row=quad*4+reg (verified)
    const size_t base = ((size_t)(mtile * KS + ks)) * 64 * T_PAD;
    EPI(0); EPI(1); EPI(2); EPI(3); EPI(4); EPI(5); EPI(6);
    EPI(7); EPI(8); EPI(9); EPI(10); EPI(11); EPI(12);
}

// K4: reduce K-split partials + class/bbox/giou + assemble final cost.
__global__ void combine_kernel(const float* __restrict__ pred_logits,
                               const float* __restrict__ pred_boxes,
                               const int*   __restrict__ tgt_ids,
                               const float* __restrict__ tgt_bbox,
                               const float* __restrict__ P1, const float* __restrict__ P2,
                               const float* __restrict__ sig_rs, const float* __restrict__ l1p_rs,
                               const float* __restrict__ tgt_sum,
                               float* __restrict__ out) {
    const int e = blockIdx.x * 256 + threadIdx.x;
    if (e >= N_PRED * N_TGT) return;
    const int n = e / N_TGT, t = e - n * N_TGT;
    const int mtile = n >> 6, mrow = n & 63;

    const size_t pb = ((size_t)mtile * KS * 64 + mrow) * T_PAD + t;
    float s1 = 0.f, s2 = 0.f;
    for (int ks = 0; ks < KS; ks++) {
        s1 += P1[pb + (size_t)ks * 64 * T_PAD];
        s2 += P2[pb + (size_t)ks * 64 * T_PAD];
    }
    // dice
    const float denom = sig_rs[n] + tgt_sum[t];
    const float cost_dice = -(2.f * s1 + 1.f) / (fmaxf(denom, 1e-6f) + 1.f);
    // mask BCE: -(S2 + rowsum(log_1mp))/HW
    const float cost_mask = -(s2 + l1p_rs[n]) / (float)HW;
    // class
    const int id = tgt_ids[t];
    const float lg = pred_logits[(size_t)n * NCLS + id];
    const float p = 1.f / (1.f + __expf(-lg));
    // bbox L1
    const float4 ob = *(const float4*)(pred_boxes + (size_t)n * 4);
    const float4 tb = *(const float4*)(tgt_bbox + (size_t)t * 4);
    const float l1 = fabsf(ob.x - tb.x) + fabsf(ob.y - tb.y) + fabsf(ob.z - tb.z) + fabsf(ob.w - tb.w);
    // giou
    const float ax0 = ob.x - 0.5f*ob.z, ay0 = ob.y - 0.5f*ob.w;
    const float ax1 = ob.x + 0.5f*ob.z, ay1 = ob.y + 0.5f*ob.w;
    const float bx0 = tb.x - 0.5f*tb.z, by0 = tb.y - 0.5f*tb.w;
    const float bx1 = tb.x + 0.5f*tb.z, by1 = tb.y + 0.5f*tb.w;
    const float areaA = (ax1 - ax0) * (ay1 - ay0);
    const float areaB = (bx1 - bx0) * (by1 - by0);
    const float iw = fmaxf(fminf(ax1, bx1) - fmaxf(ax0, bx0), 0.f);
    const float ih = fmaxf(fminf(ay1, by1) - fmaxf(ay0, by0), 0.f);
    const float inter = iw * ih;
    const float uni = areaA + areaB - inter;
    const float iou = inter / uni;
    const float cw = fmaxf(fmaxf(ax1, bx1) - fminf(ax0, bx0), 0.f);
    const float ch = fmaxf(fmaxf(ay1, by1) - fminf(ay0, by0), 0.f);
    const float areaC = cw * ch;
    const float giou = iou - (areaC - uni) / areaC;

    out[e] = 5.f * l1 + 2.f * (-giou) + 2.f * (-p) + 2.f * cost_mask + 2.f * cost_dice;
}

extern "C" void kernel_launch(void* const* d_in, const int* in_sizes, int n_in,
                              void* d_out, int out_size, void* d_ws, size_t ws_size,
                              hipStream_t stream) {
    const float* pred_logits = (const float*)d_in[0];
    const float* pred_boxes  = (const float*)d_in[1];
    const float* pred_masks  = (const float*)d_in[2];
    const int*   tgt_ids     = (const int*)d_in[3];
    const float* tgt_bbox    = (const float*)d_in[4];
    const float* tgt_masks   = (const float*)d_in[5];
    float* out = (float*)d_out;

    // workspace carving (~61.3 MB total, same footprint as the passing round-1 layout)
    char* ws = (char*)d_ws;
    size_t off = 0;
    unsigned short* tgt_bf = (unsigned short*)(ws + off);
    off += (size_t)T_PAD * K_TOT * sizeof(unsigned short);       // 10,649,600
    off = (off + 255) & ~(size_t)255;
    float* tgt_sum = (float*)(ws + off);                          // [208]  (atomic -> memset)
    float* sig_rs  = tgt_sum + T_PAD;                             // [1200] (full write, no memset)
    float* l1p_rs  = sig_rs + N_PRED;                             // [1200]
    off += (size_t)(T_PAD + 2 * N_PRED) * sizeof(float);
    off = (off + 255) & ~(size_t)255;
    float* P1 = (float*)(ws + off);
    off += (size_t)MT * KS * 64 * T_PAD * sizeof(float);          // 25,292,800
    float* P2 = (float*)(ws + off);
    off += (size_t)MT * KS * 64 * T_PAD * sizeof(float);

    hipMemsetAsync(tgt_sum, 0, T_PAD * sizeof(float), stream);
    hipLaunchKernelGGL(resize_kernel, dim3(4, T_PAD), dim3(256), 0, stream,
                       tgt_masks, tgt_bf, tgt_sum);
    hipLaunchKernelGGL(rowsum_kernel, dim3(N_PRED), dim3(256), 0, stream,
                       pred_masks, sig_rs, l1p_rs);
    hipLaunchKernelGGL(gemm_kernel, dim3(KS, MT), dim3(256), 0, stream,
                       pred_masks, tgt_bf, P1, P2);
    hipLaunchKernelGGL(combine_kernel, dim3((N_PRED * N_TGT + 255) / 256), dim3(256), 0, stream,
                       pred_logits, pred_boxes, tgt_ids, tgt_bbox,
                       P1, P2, sig_rs, l1p_rs, tgt_sum, out);
}

// Round 3
// 285.002 us; speedup vs baseline: 2.2861x; 1.0921x over previous
//
#include <hip/hip_runtime.h>
#include <math.h>

// Problem constants
#define N_PRED 1200      // bs*Q
#define N_TGT  200
#define T_PAD  208       // 13 tiles of 16
#define NCLS   80
#define W_OUT  160
#define W_IN   320
#define HW     25600     // 160*160 == K of the GEMMs
#define K_TOT  25600
#define KS     25        // K-split factor
#define K_CHUNK 1024     // K_TOT / KS
#define BK     64        // K per LDS stage
#define MT     19        // ceil(1200/64) M-tiles of 64
#define LDA    72        // LDS row stride in ushorts: 144 B/row -> 16B-aligned
#define LDB    72
#define PROW   (2 * T_PAD)   // interleaved {S,X} partial row stride (floats)

typedef __bf16 bf16x8 __attribute__((ext_vector_type(8)));
typedef float  f32x4  __attribute__((ext_vector_type(4)));

__device__ __forceinline__ unsigned short f2bf(float f) {
    unsigned int u = __float_as_uint(f);
    u = u + 0x7FFFu + ((u >> 16) & 1u);   // round-to-nearest-even
    return (unsigned short)(u >> 16);
}

// jax.image.resize(antialias=True, bilinear, 320->160): 4 taps, weights
// {1,3,3,1}/8 interior; boundary renormalized ({3,3,1}/7).
__device__ __forceinline__ void taps(int i, int& i0, float w[4]) {
    if (i == 0)            { i0 = 0;       w[0]=3.f/7.f; w[1]=3.f/7.f; w[2]=1.f/7.f; w[3]=0.f; }
    else if (i == W_OUT-1) { i0 = 2*i - 2; w[0]=0.f;     w[1]=1.f/7.f; w[2]=3.f/7.f; w[3]=3.f/7.f; }
    else                   { i0 = 2*i - 1; w[0]=0.125f;  w[1]=0.375f;  w[2]=0.375f;  w[3]=0.125f; }
}

// K1 prep: resize tgt masks -> bf16 [T_PAD][25600] + per-quarter colsums
// (no atomics, no memset) + zero sig_rs/l1p_rs in the pad-row blocks.
// grid (4, T_PAD) x 256.
__global__ void prep_kernel(const float* __restrict__ tm,
                            unsigned short* __restrict__ tgt_bf,
                            float* __restrict__ tgt_sumP,   // [4][T_PAD]
                            float* __restrict__ sig_rs,     // [N_PRED] zeroed here
                            float* __restrict__ l1p_rs) {   // [N_PRED] zeroed here
    const int t = blockIdx.y, q = blockIdx.x, tid = threadIdx.x;
    if (t >= N_TGT) {   // zero pad rows of B + zero the rowsum arrays (ws is 0xAA)
        uint4 z = make_uint4(0,0,0,0);
        uint4* dst = (uint4*)(tgt_bf + (size_t)t * HW) + q * (HW/8/4);
        for (int u = tid; u < HW/8/4; u += 256) dst[u] = z;
        if (q == 0) {
            const int base = (t - N_TGT) * 150;   // 8 blocks x 150 = 1200
            if (tid < 150) { sig_rs[base + tid] = 0.f; l1p_rs[base + tid] = 0.f; }
        }
        if (tid == 0) tgt_sumP[q * T_PAD + t] = 0.f;
        return;
    }
    const float* src = tm + (size_t)t * (W_IN * W_IN);
    float part = 0.f;
    const int p0 = q * (HW/4);
    for (int pp = tid; pp < HW/4; pp += 256) {
        const int p = p0 + pp;
        const int i = p / W_OUT, j = p % W_OUT;
        int r0, c0; float wr[4], wc[4];
        taps(i, r0, wr); taps(j, c0, wc);
        float v = 0.f;
        #pragma unroll
        for (int a = 0; a < 4; a++) {
            const float* row = src + (size_t)(r0 + a) * W_IN + c0;
            float h = wc[0]*row[0] + wc[1]*row[1] + wc[2]*row[2] + wc[3]*row[3];
            v += wr[a] * h;
        }
        tgt_bf[(size_t)t * HW + p] = f2bf(v);
        part += v;
    }
    __shared__ float red[256];
    red[tid] = part; __syncthreads();
    for (int s = 128; s > 0; s >>= 1) { if (tid < s) red[tid] += red[tid + s]; __syncthreads(); }
    if (tid == 0) tgt_sumP[q * T_PAD + t] = red[0];
}

// ---- K2: fused dual GEMM + in-loop rowsums of sigma and -softplus ----
#define DECL13(p) f32x4 p##0={0,0,0,0}, p##1={0,0,0,0}, p##2={0,0,0,0}, p##3={0,0,0,0}, \
    p##4={0,0,0,0}, p##5={0,0,0,0}, p##6={0,0,0,0}, p##7={0,0,0,0}, p##8={0,0,0,0}, \
    p##9={0,0,0,0}, p##10={0,0,0,0}, p##11={0,0,0,0}, p##12={0,0,0,0}

#define STEP(tt) { bf16x8 b = *(const bf16x8*)&ldsB[((tt)*16 + l16) * LDB + koff]; \
    accS##tt = __builtin_amdgcn_mfma_f32_16x16x32_bf16(aS, b, accS##tt, 0, 0, 0); \
    accX##tt = __builtin_amdgcn_mfma_f32_16x16x32_bf16(aX, b, accX##tt, 0, 0, 0); }

// convert + stage one row-group; accumulate sigma-sum and -softplus-sum
#define CONVW(J, RA) { \
    const float x0 = RA.x, x1 = RA.y, x2 = RA.z, x3 = RA.w; \
    const float t0 = __expf(-fabsf(x0)), t1 = __expf(-fabsf(x1)); \
    const float t2 = __expf(-fabsf(x2)), t3 = __expf(-fabsf(x3)); \
    const float i0 = __builtin_amdgcn_rcpf(1.f + t0), i1 = __builtin_amdgcn_rcpf(1.f + t1); \
    const float i2 = __builtin_amdgcn_rcpf(1.f + t2), i3 = __builtin_amdgcn_rcpf(1.f + t3); \
    const float s0 = (x0 >= 0.f) ? i0 : 1.f - i0; \
    const float s1 = (x1 >= 0.f) ? i1 : 1.f - i1; \
    const float s2 = (x2 >= 0.f) ? i2 : 1.f - i2; \
    const float s3 = (x3 >= 0.f) ? i3 : 1.f - i3; \
    sS##J += (s0 + s1) + (s2 + s3); \
    sL##J -= __logf(1.f + t0) + fmaxf(x0, 0.f) + __logf(1.f + t1) + fmaxf(x1, 0.f) \
           + __logf(1.f + t2) + fmaxf(x2, 0.f) + __logf(1.f + t3) + fmaxf(x3, 0.f); \
    const unsigned px0 = (unsigned)f2bf(x0) | ((unsigned)f2bf(x1) << 16); \
    const unsigned px1 = (unsigned)f2bf(x2) | ((unsigned)f2bf(x3) << 16); \
    const unsigned ps0 = (unsigned)f2bf(s0) | ((unsigned)f2bf(s1) << 16); \
    const unsigned ps1 = (unsigned)f2bf(s2) | ((unsigned)f2bf(s3) << 16); \
    *(uint2*)&ldsAX[((J)*16 + arow) * LDA + ac * 4] = make_uint2(px0, px1); \
    *(uint2*)&ldsAS[((J)*16 + arow) * LDA + ac * 4] = make_uint2(ps0, ps1); }

// epilogue: C/D layout col=lane&15, row=quad*4+reg; interleaved {S,X} float2
#define EPI(tt) { const size_t b0 = base + (size_t)(wave * 16 + quad * 4) * PROW + 2 * ((tt) * 16 + l16); \
    *(float2*)&P[b0           ] = make_float2(accS##tt[0], accX##tt[0]); \
    *(float2*)&P[b0 +     PROW] = make_float2(accS##tt[1], accX##tt[1]); \
    *(float2*)&P[b0 + 2 * PROW] = make_float2(accS##tt[2], accX##tt[2]); \
    *(float2*)&P[b0 + 3 * PROW] = make_float2(accS##tt[3], accX##tt[3]); }

__global__ __launch_bounds__(256, 2)
void gemm_kernel(const float* __restrict__ pm,
                 const unsigned short* __restrict__ tgt_bf,
                 float* __restrict__ P,
                 float* __restrict__ sig_rs, float* __restrict__ l1p_rs) {
    const int ks = blockIdx.x, mtile = blockIdx.y;
    const int tid = threadIdx.x;
    const int wave = tid >> 6, lane = tid & 63;
    const int quad = lane >> 4, l16 = lane & 15;

    __shared__ unsigned short ldsAX[64 * LDA];
    __shared__ unsigned short ldsAS[64 * LDA];
    __shared__ unsigned short ldsB[T_PAD * LDB];

    DECL13(accS);
    DECL13(accX);
    float sS0 = 0.f, sS1 = 0.f, sS2 = 0.f, sS3 = 0.f;
    float sL0 = 0.f, sL1 = 0.f, sL2 = 0.f, sL3 = 0.f;

    const int m0 = mtile * 64;
    const int arow = tid >> 4;   // 0..15: row within 16-row group
    const int ac   = tid & 15;   // float4 column index
    const int k0   = ks * K_CHUNK;

    // Clamped A row pointers (rows >= N_PRED read row 1199; outputs never consumed)
    int r0i = m0 + 0*16 + arow; if (r0i > N_PRED-1) r0i = N_PRED-1;
    int r1i = m0 + 1*16 + arow; if (r1i > N_PRED-1) r1i = N_PRED-1;
    int r2i = m0 + 2*16 + arow; if (r2i > N_PRED-1) r2i = N_PRED-1;
    int r3i = m0 + 3*16 + arow; if (r3i > N_PRED-1) r3i = N_PRED-1;
    const float* ap0 = pm + (size_t)r0i * K_TOT + ac * 4;
    const float* ap1 = pm + (size_t)r1i * K_TOT + ac * 4;
    const float* ap2 = pm + (size_t)r2i * K_TOT + ac * 4;
    const float* ap3 = pm + (size_t)r3i * K_TOT + ac * 4;

    const int bu = tid;   // B staging: u = tid + i*256; row u>>3, ush-col (u&7)*8

    // ---- prefetch tile 0 ----
    float4 rA0 = *(const float4*)(ap0 + k0);
    float4 rA1 = *(const float4*)(ap1 + k0);
    float4 rA2 = *(const float4*)(ap2 + k0);
    float4 rA3 = *(const float4*)(ap3 + k0);
    uint4 rB0, rB1, rB2, rB3, rB4, rB5, rB6;
    {
        const unsigned short* bp = tgt_bf + k0;
        rB0 = *(const uint4*)(bp + (size_t)((bu       ) >> 3) * K_TOT + ((bu       ) & 7) * 8);
        rB1 = *(const uint4*)(bp + (size_t)((bu +  256) >> 3) * K_TOT + ((bu +  256) & 7) * 8);
        rB2 = *(const uint4*)(bp + (size_t)((bu +  512) >> 3) * K_TOT + ((bu +  512) & 7) * 8);
        rB3 = *(const uint4*)(bp + (size_t)((bu +  768) >> 3) * K_TOT + ((bu +  768) & 7) * 8);
        rB4 = *(const uint4*)(bp + (size_t)((bu + 1024) >> 3) * K_TOT + ((bu + 1024) & 7) * 8);
        rB5 = *(const uint4*)(bp + (size_t)((bu + 1280) >> 3) * K_TOT + ((bu + 1280) & 7) * 8);
        if (tid < 128)
            rB6 = *(const uint4*)(bp + (size_t)((bu + 1536) >> 3) * K_TOT + ((bu + 1536) & 7) * 8);
    }

    for (int ki = 0; ki < K_CHUNK / BK; ki++) {
        __syncthreads();                       // previous MFMA phase done -> LDS reusable
        CONVW(0, rA0); CONVW(1, rA1); CONVW(2, rA2); CONVW(3, rA3);
        *(uint4*)&ldsB[((bu       ) >> 3) * LDB + ((bu       ) & 7) * 8] = rB0;
        *(uint4*)&ldsB[((bu +  256) >> 3) * LDB + ((bu +  256) & 7) * 8] = rB1;
        *(uint4*)&ldsB[((bu +  512) >> 3) * LDB + ((bu +  512) & 7) * 8] = rB2;
        *(uint4*)&ldsB[((bu +  768) >> 3) * LDB + ((bu +  768) & 7) * 8] = rB3;
        *(uint4*)&ldsB[((bu + 1024) >> 3) * LDB + ((bu + 1024) & 7) * 8] = rB4;
        *(uint4*)&ldsB[((bu + 1280) >> 3) * LDB + ((bu + 1280) & 7) * 8] = rB5;
        if (tid < 128)
            *(uint4*)&ldsB[((bu + 1536) >> 3) * LDB + ((bu + 1536) & 7) * 8] = rB6;
        __syncthreads();
        // next tile's global loads overlap the MFMA phase below
        if (ki != K_CHUNK / BK - 1) {
            const int kn = k0 + (ki + 1) * BK;
            rA0 = *(const float4*)(ap0 + kn);
            rA1 = *(const float4*)(ap1 + kn);
            rA2 = *(const float4*)(ap2 + kn);
            rA3 = *(const float4*)(ap3 + kn);
            const unsigned short* bp = tgt_bf + kn;
            rB0 = *(const uint4*)(bp + (size_t)((bu       ) >> 3) * K_TOT + ((bu       ) & 7) * 8);
            rB1 = *(const uint4*)(bp + (size_t)((bu +  256) >> 3) * K_TOT + ((bu +  256) & 7) * 8);
            rB2 = *(const uint4*)(bp + (size_t)((bu +  512) >> 3) * K_TOT + ((bu +  512) & 7) * 8);
            rB3 = *(const uint4*)(bp + (size_t)((bu +  768) >> 3) * K_TOT + ((bu +  768) & 7) * 8);
            rB4 = *(const uint4*)(bp + (size_t)((bu + 1024) >> 3) * K_TOT + ((bu + 1024) & 7) * 8);
            rB5 = *(const uint4*)(bp + (size_t)((bu + 1280) >> 3) * K_TOT + ((bu + 1280) & 7) * 8);
            if (tid < 128)
                rB6 = *(const uint4*)(bp + (size_t)((bu + 1536) >> 3) * K_TOT + ((bu + 1536) & 7) * 8);
        }
        // MFMA phase: A frag = A[m=lane&15][k=quad*8+j]; B frag = tgt[t=lane&15][k=quad*8+j]
        #pragma unroll
        for (int kk = 0; kk < 2; kk++) {
            const int koff = kk * 32 + quad * 8;
            bf16x8 aX = *(const bf16x8*)&ldsAX[(wave * 16 + l16) * LDA + koff];
            bf16x8 aS = *(const bf16x8*)&ldsAS[(wave * 16 + l16) * LDA + koff];
            STEP(0); STEP(1); STEP(2); STEP(3); STEP(4); STEP(5); STEP(6);
            STEP(7); STEP(8); STEP(9); STEP(10); STEP(11); STEP(12);
        }
    }
    // partial-C epilogue
    const size_t base = ((size_t)(mtile * KS + ks)) * 64 * PROW;
    EPI(0); EPI(1); EPI(2); EPI(3); EPI(4); EPI(5); EPI(6);
    EPI(7); EPI(8); EPI(9); EPI(10); EPI(11); EPI(12);

    // rowsum reduction over the 16 ac-lanes (low 4 lane bits), then 1 atomic/row
    #pragma unroll
    for (int m = 1; m < 16; m <<= 1) {
        sS0 += __shfl_xor(sS0, m); sS1 += __shfl_xor(sS1, m);
        sS2 += __shfl_xor(sS2, m); sS3 += __shfl_xor(sS3, m);
        sL0 += __shfl_xor(sL0, m); sL1 += __shfl_xor(sL1, m);
        sL2 += __shfl_xor(sL2, m); sL3 += __shfl_xor(sL3, m);
    }
    if (l16 == 0) {
        const int rg0 = m0 + 0*16 + arow, rg1 = m0 + 1*16 + arow;
        const int rg2 = m0 + 2*16 + arow, rg3 = m0 + 3*16 + arow;
        if (rg0 < N_PRED) { atomicAdd(sig_rs + rg0, sS0); atomicAdd(l1p_rs + rg0, sL0); }
        if (rg1 < N_PRED) { atomicAdd(sig_rs + rg1, sS1); atomicAdd(l1p_rs + rg1, sL1); }
        if (rg2 < N_PRED) { atomicAdd(sig_rs + rg2, sS2); atomicAdd(l1p_rs + rg2, sL2); }
        if (rg3 < N_PRED) { atomicAdd(sig_rs + rg3, sS3); atomicAdd(l1p_rs + rg3, sL3); }
    }
}

// K3: reduce K-split partials + class/bbox/giou + assemble final cost.
__global__ void combine_kernel(const float* __restrict__ pred_logits,
                               const float* __restrict__ pred_boxes,
                               const int*   __restrict__ tgt_ids,
                               const float* __restrict__ tgt_bbox,
                               const float* __restrict__ P,
                               const float* __restrict__ sig_rs, const float* __restrict__ l1p_rs,
                               const float* __restrict__ tgt_sumP,
                               float* __restrict__ out) {
    const int e = blockIdx.x * 256 + threadIdx.x;
    if (e >= N_PRED * N_TGT) return;
    const int n = e / N_TGT, t = e - n * N_TGT;
    const int mtile = n >> 6, mrow = n & 63;

    const size_t pb = ((size_t)mtile * KS * 64 + mrow) * PROW + 2 * t;
    float s1 = 0.f, s2 = 0.f;
    for (int ks = 0; ks < KS; ks++) {
        float2 v = *(const float2*)&P[pb + (size_t)ks * 64 * PROW];
        s1 += v.x; s2 += v.y;
    }
    // dice
    const float tsum = tgt_sumP[t] + tgt_sumP[T_PAD + t] + tgt_sumP[2*T_PAD + t] + tgt_sumP[3*T_PAD + t];
    const float denom = sig_rs[n] + tsum;
    const float cost_dice = -(2.f * s1 + 1.f) / (fmaxf(denom, 1e-6f) + 1.f);
    // mask BCE: -(S2 + rowsum(log_1mp))/HW
    const float cost_mask = -(s2 + l1p_rs[n]) / (float)HW;
    // class
    const int id = tgt_ids[t];
    const float lg = pred_logits[(size_t)n * NCLS + id];
    const float p = 1.f / (1.f + __expf(-lg));
    // bbox L1
    const float4 ob = *(const float4*)(pred_boxes + (size_t)n * 4);
    const float4 tb = *(const float4*)(tgt_bbox + (size_t)t * 4);
    const float l1 = fabsf(ob.x - tb.x) + fabsf(ob.y - tb.y) + fabsf(ob.z - tb.z) + fabsf(ob.w - tb.w);
    // giou
    const float ax0 = ob.x - 0.5f*ob.z, ay0 = ob.y - 0.5f*ob.w;
    const float ax1 = ob.x + 0.5f*ob.z, ay1 = ob.y + 0.5f*ob.w;
    const float bx0 = tb.x - 0.5f*tb.z, by0 = tb.y - 0.5f*tb.w;
    const float bx1 = tb.x + 0.5f*tb.z, by1 = tb.y + 0.5f*tb.w;
    const float areaA = (ax1 - ax0) * (ay1 - ay0);
    const float areaB = (bx1 - bx0) * (by1 - by0);
    const float iw = fmaxf(fminf(ax1, bx1) - fmaxf(ax0, bx0), 0.f);
    const float ih = fmaxf(fminf(ay1, by1) - fmaxf(ay0, by0), 0.f);
    const float inter = iw * ih;
    const float uni = areaA + areaB - inter;
    const float iou = inter / uni;
    const float cw = fmaxf(fmaxf(ax1, bx1) - fminf(ax0, bx0), 0.f);
    const float ch = fmaxf(fmaxf(ay1, by1) - fminf(ay0, by0), 0.f);
    const float areaC = cw * ch;
    const float giou = iou - (areaC - uni) / areaC;

    out[e] = 5.f * l1 + 2.f * (-giou) + 2.f * (-p) + 2.f * cost_mask + 2.f * cost_dice;
}

extern "C" void kernel_launch(void* const* d_in, const int* in_sizes, int n_in,
                              void* d_out, int out_size, void* d_ws, size_t ws_size,
                              hipStream_t stream) {
    const float* pred_logits = (const float*)d_in[0];
    const float* pred_boxes  = (const float*)d_in[1];
    const float* pred_masks  = (const float*)d_in[2];
    const int*   tgt_ids     = (const int*)d_in[3];
    const float* tgt_bbox    = (const float*)d_in[4];
    const float* tgt_masks   = (const float*)d_in[5];
    float* out = (float*)d_out;

    // workspace carving (~61.3 MB; everything 0xAA-poisoned is re-written/zeroed)
    char* ws = (char*)d_ws;
    size_t off = 0;
    unsigned short* tgt_bf = (unsigned short*)(ws + off);
    off += (size_t)T_PAD * K_TOT * sizeof(unsigned short);       // 10,649,600
    off = (off + 255) & ~(size_t)255;
    float* tgt_sumP = (float*)(ws + off);                         // [4][208]
    float* sig_rs   = tgt_sumP + 4 * T_PAD;                       // [1200]
    float* l1p_rs   = sig_rs + N_PRED;                            // [1200]
    off += (size_t)(4 * T_PAD + 2 * N_PRED) * sizeof(float);
    off = (off + 255) & ~(size_t)255;
    float* P = (float*)(ws + off);                                // interleaved partials
    off += (size_t)MT * KS * 64 * PROW * sizeof(float);           // 50,585,600

    hipLaunchKernelGGL(prep_kernel, dim3(4, T_PAD), dim3(256), 0, stream,
                       tgt_masks, tgt_bf, tgt_sumP, sig_rs, l1p_rs);
    hipLaunchKernelGGL(gemm_kernel, dim3(KS, MT), dim3(256), 0, stream,
                       pred_masks, tgt_bf, P, sig_rs, l1p_rs);
    hipLaunchKernelGGL(combine_kernel, dim3((N_PRED * N_TGT + 255) / 256), dim3(256), 0, stream,
                       pred_logits, pred_boxes, tgt_ids, tgt_bbox,
                       P, sig_rs, l1p_rs, tgt_sumP, out);
}

// Round 4
// 280.199 us; speedup vs baseline: 2.3252x; 1.0171x over previous
//
#include <hip/hip_runtime.h>
#include <math.h>

// Problem constants
#define N_PRED 1200      // bs*Q
#define N_TGT  200
#define T_PAD  208       // 13 tiles of 16
#define NCLS   80
#define W_OUT  160
#define W_IN   320
#define HW     25600     // 160*160 == K of the GEMMs
#define K_TOT  25600
#define KS     25        // K-split factor
#define K_CHUNK 1024     // K_TOT / KS
#define BK     64        // K per LDS stage
#define MT     19        // ceil(1200/64) M-tiles of 64
#define PROW   (2 * T_PAD)   // interleaved {S,X} partial row stride (floats)

// LDS: stride 64 ushorts (128 B = 32 banks), XOR swizzle on 16B groups:
// element (row, col) stored at row*64 + ((col>>3) ^ (row&7))*8 + (col&7).
// Writes and b128 reads are then conflict-free (128 B/clk floor).

typedef __bf16 bf16x8 __attribute__((ext_vector_type(8)));
typedef float  f32x4  __attribute__((ext_vector_type(4)));

__device__ __forceinline__ unsigned short f2bf(float f) {
    unsigned int u = __float_as_uint(f);
    u = u + 0x7FFFu + ((u >> 16) & 1u);   // round-to-nearest-even
    return (unsigned short)(u >> 16);
}

#if __has_builtin(__builtin_amdgcn_cvt_pk_bf16_f32)
typedef __bf16 bf16x2 __attribute__((ext_vector_type(2)));
__device__ __forceinline__ unsigned pk_bf16(float a, float b) {
    bf16x2 v = __builtin_amdgcn_cvt_pk_bf16_f32(a, b);
    return *(unsigned*)&v;
}
#else
__device__ __forceinline__ unsigned pk_bf16(float a, float b) {
    return (unsigned)f2bf(a) | ((unsigned)f2bf(b) << 16);
}
#endif

// jax.image.resize(antialias=True, bilinear, 320->160): 4 taps, weights
// {1,3,3,1}/8 interior; boundary renormalized ({3,3,1}/7).
__device__ __forceinline__ void taps(int i, int& i0, float w[4]) {
    if (i == 0)            { i0 = 0;       w[0]=3.f/7.f; w[1]=3.f/7.f; w[2]=1.f/7.f; w[3]=0.f; }
    else if (i == W_OUT-1) { i0 = 2*i - 2; w[0]=0.f;     w[1]=1.f/7.f; w[2]=3.f/7.f; w[3]=3.f/7.f; }
    else                   { i0 = 2*i - 1; w[0]=0.125f;  w[1]=0.375f;  w[2]=0.375f;  w[3]=0.125f; }
}

// K1 prep: resize tgt masks -> bf16 [T_PAD][25600] + per-quarter colsums
// (no atomics, no memset) + zero sig_rs/l1p_rs in the pad-row blocks.
// grid (4, T_PAD) x 256.
__global__ void prep_kernel(const float* __restrict__ tm,
                            unsigned short* __restrict__ tgt_bf,
                            float* __restrict__ tgt_sumP,   // [4][T_PAD]
                            float* __restrict__ sig_rs,     // [N_PRED] zeroed here
                            float* __restrict__ l1p_rs) {   // [N_PRED] zeroed here
    const int t = blockIdx.y, q = blockIdx.x, tid = threadIdx.x;
    if (t >= N_TGT) {   // zero pad rows of B + zero the rowsum arrays (ws is 0xAA)
        uint4 z = make_uint4(0,0,0,0);
        uint4* dst = (uint4*)(tgt_bf + (size_t)t * HW) + q * (HW/8/4);
        for (int u = tid; u < HW/8/4; u += 256) dst[u] = z;
        if (q == 0) {
            const int base = (t - N_TGT) * 150;   // 8 blocks x 150 = 1200
            if (tid < 150) { sig_rs[base + tid] = 0.f; l1p_rs[base + tid] = 0.f; }
        }
        if (tid == 0) tgt_sumP[q * T_PAD + t] = 0.f;
        return;
    }
    const float* src = tm + (size_t)t * (W_IN * W_IN);
    float part = 0.f;
    const int p0 = q * (HW/4);
    for (int pp = tid; pp < HW/4; pp += 256) {
        const int p = p0 + pp;
        const int i = p / W_OUT, j = p % W_OUT;
        int r0, c0; float wr[4], wc[4];
        taps(i, r0, wr); taps(j, c0, wc);
        float v = 0.f;
        #pragma unroll
        for (int a = 0; a < 4; a++) {
            const float* row = src + (size_t)(r0 + a) * W_IN + c0;
            float h = wc[0]*row[0] + wc[1]*row[1] + wc[2]*row[2] + wc[3]*row[3];
            v += wr[a] * h;
        }
        tgt_bf[(size_t)t * HW + p] = f2bf(v);
        part += v;
    }
    __shared__ float red[256];
    red[tid] = part; __syncthreads();
    for (int s = 128; s > 0; s >>= 1) { if (tid < s) red[tid] += red[tid + s]; __syncthreads(); }
    if (tid == 0) tgt_sumP[q * T_PAD + t] = red[0];
}

// ---- K2: fused dual GEMM + in-loop rowsums of sigma and -softplus ----
#define DECL13(p) f32x4 p##0={0,0,0,0}, p##1={0,0,0,0}, p##2={0,0,0,0}, p##3={0,0,0,0}, \
    p##4={0,0,0,0}, p##5={0,0,0,0}, p##6={0,0,0,0}, p##7={0,0,0,0}, p##8={0,0,0,0}, \
    p##9={0,0,0,0}, p##10={0,0,0,0}, p##11={0,0,0,0}, p##12={0,0,0,0}

// swizzled b128 read offset: same column swizzle for A and B (row&7 == l16&7)
#define STEP(tt) { bf16x8 b = *(const bf16x8*)&ldsB[((tt)*16 + l16) * 64 + co]; \
    accS##tt = __builtin_amdgcn_mfma_f32_16x16x32_bf16(aS, b, accS##tt, 0, 0, 0); \
    accX##tt = __builtin_amdgcn_mfma_f32_16x16x32_bf16(aX, b, accX##tt, 0, 0, 0); }

// convert + stage one row-group; accumulate sigma-sum and -softplus-sum.
// |x| < ~7 so exp(-x) never overflows; softplus(x) = x + log(1+exp(-x)).
#define CONVW(J, RA) { \
    const float x0 = RA.x, x1 = RA.y, x2 = RA.z, x3 = RA.w; \
    const float e0 = __expf(-x0), e1 = __expf(-x1), e2 = __expf(-x2), e3 = __expf(-x3); \
    const float u0 = 1.f + e0, u1 = 1.f + e1, u2 = 1.f + e2, u3 = 1.f + e3; \
    const float s0 = __builtin_amdgcn_rcpf(u0), s1 = __builtin_amdgcn_rcpf(u1); \
    const float s2 = __builtin_amdgcn_rcpf(u2), s3 = __builtin_amdgcn_rcpf(u3); \
    sS##J += (s0 + s1) + (s2 + s3); \
    sL##J -= (x0 + __logf(u0)) + (x1 + __logf(u1)) + (x2 + __logf(u2)) + (x3 + __logf(u3)); \
    const int rl_ = (J)*16 + arow; \
    const int ao_ = rl_*64 + (((ac >> 1) ^ (rl_ & 7)) * 8) + (ac & 1) * 4; \
    *(uint2*)&ldsAX[ao_] = make_uint2(pk_bf16(x0, x1), pk_bf16(x2, x3)); \
    *(uint2*)&ldsAS[ao_] = make_uint2(pk_bf16(s0, s1), pk_bf16(s2, s3)); }

// B LDS staging address for linear index U (row U>>3, 16B group U&7, swizzled)
#define BADDR(U) ((((U) >> 3) * 64) + (((((U) & 7)) ^ (((U) >> 3) & 7)) * 8))

// epilogue: C/D layout col=lane&15, row=quad*4+reg; interleaved {S,X} float2
#define EPI(tt) { const size_t b0 = base + (size_t)(wave * 16 + quad * 4) * PROW + 2 * ((tt) * 16 + l16); \
    *(float2*)&P[b0           ] = make_float2(accS##tt[0], accX##tt[0]); \
    *(float2*)&P[b0 +     PROW] = make_float2(accS##tt[1], accX##tt[1]); \
    *(float2*)&P[b0 + 2 * PROW] = make_float2(accS##tt[2], accX##tt[2]); \
    *(float2*)&P[b0 + 3 * PROW] = make_float2(accS##tt[3], accX##tt[3]); }

__global__ __launch_bounds__(256, 2)
void gemm_kernel(const float* __restrict__ pm,
                 const unsigned short* __restrict__ tgt_bf,
                 float* __restrict__ P,
                 float* __restrict__ sig_rs, float* __restrict__ l1p_rs) {
    const int ks = blockIdx.x, mtile = blockIdx.y;
    const int tid = threadIdx.x;
    const int wave = tid >> 6, lane = tid & 63;
    const int quad = lane >> 4, l16 = lane & 15;
    const int l7 = l16 & 7;

    __shared__ unsigned short ldsAX[64 * 64];
    __shared__ unsigned short ldsAS[64 * 64];
    __shared__ unsigned short ldsB[T_PAD * 64];

    DECL13(accS);
    DECL13(accX);
    float sS0 = 0.f, sS1 = 0.f, sS2 = 0.f, sS3 = 0.f;
    float sL0 = 0.f, sL1 = 0.f, sL2 = 0.f, sL3 = 0.f;

    const int m0 = mtile * 64;
    const int arow = tid >> 4;   // 0..15: row within 16-row group
    const int ac   = tid & 15;   // float4 column index
    const int k0   = ks * K_CHUNK;

    // Clamped A row pointers (rows >= N_PRED read row 1199; outputs never consumed)
    int r0i = m0 + 0*16 + arow; if (r0i > N_PRED-1) r0i = N_PRED-1;
    int r1i = m0 + 1*16 + arow; if (r1i > N_PRED-1) r1i = N_PRED-1;
    int r2i = m0 + 2*16 + arow; if (r2i > N_PRED-1) r2i = N_PRED-1;
    int r3i = m0 + 3*16 + arow; if (r3i > N_PRED-1) r3i = N_PRED-1;
    const float* ap0 = pm + (size_t)r0i * K_TOT + ac * 4;
    const float* ap1 = pm + (size_t)r1i * K_TOT + ac * 4;
    const float* ap2 = pm + (size_t)r2i * K_TOT + ac * 4;
    const float* ap3 = pm + (size_t)r3i * K_TOT + ac * 4;

    const int bu = tid;   // B staging: u = tid + i*256; row u>>3, 16B group u&7

    // ---- prefetch tile 0 ----
    float4 rA0 = *(const float4*)(ap0 + k0);
    float4 rA1 = *(const float4*)(ap1 + k0);
    float4 rA2 = *(const float4*)(ap2 + k0);
    float4 rA3 = *(const float4*)(ap3 + k0);
    uint4 rB0, rB1, rB2, rB3, rB4, rB5, rB6;
    {
        const unsigned short* bp = tgt_bf + k0;
        rB0 = *(const uint4*)(bp + (size_t)((bu       ) >> 3) * K_TOT + ((bu       ) & 7) * 8);
        rB1 = *(const uint4*)(bp + (size_t)((bu +  256) >> 3) * K_TOT + ((bu +  256) & 7) * 8);
        rB2 = *(const uint4*)(bp + (size_t)((bu +  512) >> 3) * K_TOT + ((bu +  512) & 7) * 8);
        rB3 = *(const uint4*)(bp + (size_t)((bu +  768) >> 3) * K_TOT + ((bu +  768) & 7) * 8);
        rB4 = *(const uint4*)(bp + (size_t)((bu + 1024) >> 3) * K_TOT + ((bu + 1024) & 7) * 8);
        rB5 = *(const uint4*)(bp + (size_t)((bu + 1280) >> 3) * K_TOT + ((bu + 1280) & 7) * 8);
        if (tid < 128)
            rB6 = *(const uint4*)(bp + (size_t)((bu + 1536) >> 3) * K_TOT + ((bu + 1536) & 7) * 8);
    }

    for (int ki = 0; ki < K_CHUNK / BK; ki++) {
        __syncthreads();                       // previous MFMA phase done -> LDS reusable
        CONVW(0, rA0); CONVW(1, rA1); CONVW(2, rA2); CONVW(3, rA3);
        *(uint4*)&ldsB[BADDR(bu       )] = rB0;
        *(uint4*)&ldsB[BADDR(bu +  256)] = rB1;
        *(uint4*)&ldsB[BADDR(bu +  512)] = rB2;
        *(uint4*)&ldsB[BADDR(bu +  768)] = rB3;
        *(uint4*)&ldsB[BADDR(bu + 1024)] = rB4;
        *(uint4*)&ldsB[BADDR(bu + 1280)] = rB5;
        if (tid < 128)
            *(uint4*)&ldsB[BADDR(bu + 1536)] = rB6;
        __syncthreads();
        // next tile's global loads overlap the MFMA phase below
        if (ki != K_CHUNK / BK - 1) {
            const int kn = k0 + (ki + 1) * BK;
            rA0 = *(const float4*)(ap0 + kn);
            rA1 = *(const float4*)(ap1 + kn);
            rA2 = *(const float4*)(ap2 + kn);
            rA3 = *(const float4*)(ap3 + kn);
            const unsigned short* bp = tgt_bf + kn;
            rB0 = *(const uint4*)(bp + (size_t)((bu       ) >> 3) * K_TOT + ((bu       ) & 7) * 8);
            rB1 = *(const uint4*)(bp + (size_t)((bu +  256) >> 3) * K_TOT + ((bu +  256) & 7) * 8);
            rB2 = *(const uint4*)(bp + (size_t)((bu +  512) >> 3) * K_TOT + ((bu +  512) & 7) * 8);
            rB3 = *(const uint4*)(bp + (size_t)((bu +  768) >> 3) * K_TOT + ((bu +  768) & 7) * 8);
            rB4 = *(const uint4*)(bp + (size_t)((bu + 1024) >> 3) * K_TOT + ((bu + 1024) & 7) * 8);
            rB5 = *(const uint4*)(bp + (size_t)((bu + 1280) >> 3) * K_TOT + ((bu + 1280) & 7) * 8);
            if (tid < 128)
                rB6 = *(const uint4*)(bp + (size_t)((bu + 1536) >> 3) * K_TOT + ((bu + 1536) & 7) * 8);
        }
        // MFMA phase: A frag = A[m=lane&15][k=quad*8+j]; B frag = tgt[t=lane&15][k=quad*8+j]
        #pragma unroll
        for (int kk = 0; kk < 2; kk++) {
            const int co = (((kk * 4 + quad) ^ l7)) * 8;   // swizzled column offset
            bf16x8 aX = *(const bf16x8*)&ldsAX[(wave * 16 + l16) * 64 + co];
            bf16x8 aS = *(const bf16x8*)&ldsAS[(wave * 16 + l16) * 64 + co];
            STEP(0); STEP(1); STEP(2); STEP(3); STEP(4); STEP(5); STEP(6);
            STEP(7); STEP(8); STEP(9); STEP(10); STEP(11); STEP(12);
        }
    }
    // partial-C epilogue
    const size_t base = ((size_t)(mtile * KS + ks)) * 64 * PROW;
    EPI(0); EPI(1); EPI(2); EPI(3); EPI(4); EPI(5); EPI(6);
    EPI(7); EPI(8); EPI(9); EPI(10); EPI(11); EPI(12);

    // rowsum reduction over the 16 ac-lanes (low 4 lane bits), then 1 atomic/row
    #pragma unroll
    for (int m = 1; m < 16; m <<= 1) {
        sS0 += __shfl_xor(sS0, m); sS1 += __shfl_xor(sS1, m);
        sS2 += __shfl_xor(sS2, m); sS3 += __shfl_xor(sS3, m);
        sL0 += __shfl_xor(sL0, m); sL1 += __shfl_xor(sL1, m);
        sL2 += __shfl_xor(sL2, m); sL3 += __shfl_xor(sL3, m);
    }
    if (l16 == 0) {
        const int rg0 = m0 + 0*16 + arow, rg1 = m0 + 1*16 + arow;
        const int rg2 = m0 + 2*16 + arow, rg3 = m0 + 3*16 + arow;
        if (rg0 < N_PRED) { atomicAdd(sig_rs + rg0, sS0); atomicAdd(l1p_rs + rg0, sL0); }
        if (rg1 < N_PRED) { atomicAdd(sig_rs + rg1, sS1); atomicAdd(l1p_rs + rg1, sL1); }
        if (rg2 < N_PRED) { atomicAdd(sig_rs + rg2, sS2); atomicAdd(l1p_rs + rg2, sL2); }
        if (rg3 < N_PRED) { atomicAdd(sig_rs + rg3, sS3); atomicAdd(l1p_rs + rg3, sL3); }
    }
}

// K3: reduce K-split partials + class/bbox/giou + assemble final cost.
__global__ void combine_kernel(const float* __restrict__ pred_logits,
                               const float* __restrict__ pred_boxes,
                               const int*   __restrict__ tgt_ids,
                               const float* __restrict__ tgt_bbox,
                               const float* __restrict__ P,
                               const float* __restrict__ sig_rs, const float* __restrict__ l1p_rs,
                               const float* __restrict__ tgt_sumP,
                               float* __restrict__ out) {
    const int e = blockIdx.x * 256 + threadIdx.x;
    if (e >= N_PRED * N_TGT) return;
    const int n = e / N_TGT, t = e - n * N_TGT;
    const int mtile = n >> 6, mrow = n & 63;

    const size_t pb = ((size_t)mtile * KS * 64 + mrow) * PROW + 2 * t;
    float s1 = 0.f, s2 = 0.f;
    for (int ks = 0; ks < KS; ks++) {
        float2 v = *(const float2*)&P[pb + (size_t)ks * 64 * PROW];
        s1 += v.x; s2 += v.y;
    }
    // dice
    const float tsum = tgt_sumP[t] + tgt_sumP[T_PAD + t] + tgt_sumP[2*T_PAD + t] + tgt_sumP[3*T_PAD + t];
    const float denom = sig_rs[n] + tsum;
    const float cost_dice = -(2.f * s1 + 1.f) / (fmaxf(denom, 1e-6f) + 1.f);
    // mask BCE: -(S2 + rowsum(log_1mp))/HW
    const float cost_mask = -(s2 + l1p_rs[n]) / (float)HW;
    // class
    const int id = tgt_ids[t];
    const float lg = pred_logits[(size_t)n * NCLS + id];
    const float p = 1.f / (1.f + __expf(-lg));
    // bbox L1
    const float4 ob = *(const float4*)(pred_boxes + (size_t)n * 4);
    const float4 tb = *(const float4*)(tgt_bbox + (size_t)t * 4);
    const float l1 = fabsf(ob.x - tb.x) + fabsf(ob.y - tb.y) + fabsf(ob.z - tb.z) + fabsf(ob.w - tb.w);
    // giou
    const float ax0 = ob.x - 0.5f*ob.z, ay0 = ob.y - 0.5f*ob.w;
    const float ax1 = ob.x + 0.5f*ob.z, ay1 = ob.y + 0.5f*ob.w;
    const float bx0 = tb.x - 0.5f*tb.z, by0 = tb.y - 0.5f*tb.w;
    const float bx1 = tb.x + 0.5f*tb.z, by1 = tb.y + 0.5f*tb.w;
    const float areaA = (ax1 - ax0) * (ay1 - ay0);
    const float areaB = (bx1 - bx0) * (by1 - by0);
    const float iw = fmaxf(fminf(ax1, bx1) - fmaxf(ax0, bx0), 0.f);
    const float ih = fmaxf(fminf(ay1, by1) - fmaxf(ay0, by0), 0.f);
    const float inter = iw * ih;
    const float uni = areaA + areaB - inter;
    const float iou = inter / uni;
    const float cw = fmaxf(fmaxf(ax1, bx1) - fminf(ax0, bx0), 0.f);
    const float ch = fmaxf(fmaxf(ay1, by1) - fminf(ay0, by0), 0.f);
    const float areaC = cw * ch;
    const float giou = iou - (areaC - uni) / areaC;

    out[e] = 5.f * l1 + 2.f * (-giou) + 2.f * (-p) + 2.f * cost_mask + 2.f * cost_dice;
}

extern "C" void kernel_launch(void* const* d_in, const int* in_sizes, int n_in,
                              void* d_out, int out_size, void* d_ws, size_t ws_size,
                              hipStream_t stream) {
    const float* pred_logits = (const float*)d_in[0];
    const float* pred_boxes  = (const float*)d_in[1];
    const float* pred_masks  = (const float*)d_in[2];
    const int*   tgt_ids     = (const int*)d_in[3];
    const float* tgt_bbox    = (const float*)d_in[4];
    const float* tgt_masks   = (const float*)d_in[5];
    float* out = (float*)d_out;

    // workspace carving (~61.3 MB; everything 0xAA-poisoned is re-written/zeroed)
    char* ws = (char*)d_ws;
    size_t off = 0;
    unsigned short* tgt_bf = (unsigned short*)(ws + off);
    off += (size_t)T_PAD * K_TOT * sizeof(unsigned short);       // 10,649,600
    off = (off + 255) & ~(size_t)255;
    float* tgt_sumP = (float*)(ws + off);                         // [4][208]
    float* sig_rs   = tgt_sumP + 4 * T_PAD;                       // [1200]
    float* l1p_rs   = sig_rs + N_PRED;                            // [1200]
    off += (size_t)(4 * T_PAD + 2 * N_PRED) * sizeof(float);
    off = (off + 255) & ~(size_t)255;
    float* P = (float*)(ws + off);                                // interleaved partials
    off += (size_t)MT * KS * 64 * PROW * sizeof(float);           // 50,585,600

    hipLaunchKernelGGL(prep_kernel, dim3(4, T_PAD), dim3(256), 0, stream,
                       tgt_masks, tgt_bf, tgt_sumP, sig_rs, l1p_rs);
    hipLaunchKernelGGL(gemm_kernel, dim3(KS, MT), dim3(256), 0, stream,
                       pred_masks, tgt_bf, P, sig_rs, l1p_rs);
    hipLaunchKernelGGL(combine_kernel, dim3((N_PRED * N_TGT + 255) / 256), dim3(256), 0, stream,
                       pred_logits, pred_boxes, tgt_ids, tgt_bbox,
                       P, sig_rs, l1p_rs, tgt_sumP, out);
}